// Round 1
// baseline (127.831 us; speedup 1.0000x reference)
//
#include <hip/hip_runtime.h>

// ---------------------------------------------------------------------------
// PolyDecoder: out[4096,64] = polyfeats(z)[4096,37449] @ W^T + b
// Strategy: f16 MFMA GEMM with on-the-fly A-generation (Kronecker features)
// and a fragment-tiled f16 copy of W in workspace.
//
// Padded K layout (32-granular chunks; W padded with zeros):
//   kpad [0,8)      = z[0..7]          (orig 1..8)
//   kpad 8          = 1.0 const slot   (orig 0, bias folded in)
//   kpad [9,32)     = 0
//   kpad [32,96)    = z^2 (64)         (orig 9..72)
//   kpad [96,608)   = z^3 (512)        (orig 73..584)
//   kpad [608,4704) = z^4 (4096)       (orig 585..4680)
//   kpad [4704,37472)= z^5 (32768)     (orig 4681..37448)
//   kpad [37472,37504) = 0
// K32-step s = kpad/32:  s=0 deg<=1 | 1..2 deg2 | 3..18 deg3 | 19..146 deg4 |
//                        147..1170 deg5 | 1171 pad
// ---------------------------------------------------------------------------

#define TOTAL_TERMS 37449
#define NSTEP 1172          // K32 steps (incl. 1 pad step)
#define NCHUNK 586          // K64 double-buffer chunks
#define KSPLIT 32
#define MBLK 16             // 4096 / 256 rows per block

typedef _Float16 half8 __attribute__((ext_vector_type(8)));
typedef float f32x4 __attribute__((ext_vector_type(4)));

// Build Wt: fragment-tiled f16 W^T.  Layout: [step s][ntile][lane][j] where
// element = W[n = ntile*16 + (lane&15)][orig(k = s*32 + (lane>>4)*8 + j)].
// One thread per (s, ntile, lane) writes 16 contiguous bytes (coalesced).
__global__ __launch_bounds__(256) void convert_w(const float* __restrict__ W,
                                                 const float* __restrict__ bias,
                                                 _Float16* __restrict__ Wt) {
    int s    = blockIdx.x;            // 0..NSTEP-1
    int nt   = threadIdx.x >> 6;      // 0..3
    int lane = threadIdx.x & 63;
    int n    = nt * 16 + (lane & 15);
    int quad = lane >> 4;
    int kbase = s * 32 + quad * 8;
    const float* wrow = W + (size_t)n * TOTAL_TERMS;
    half8 hv;
#pragma unroll
    for (int j = 0; j < 8; ++j) {
        int kp = kbase + j;
        float v;
        if (kp < 8)            v = wrow[1 + kp];
        else if (kp == 8)      v = wrow[0] + bias[n];
        else if (kp < 32)      v = 0.f;
        else if (kp < 96)      v = wrow[9 + (kp - 32)];
        else if (kp < 608)     v = wrow[73 + (kp - 96)];
        else if (kp < 4704)    v = wrow[585 + (kp - 608)];
        else if (kp < 37472)   v = wrow[4681 + (kp - 4704)];
        else                   v = 0.f;
        hv[j] = (_Float16)v;
    }
    *(half8*)(Wt + ((size_t)(s * 4 + nt) * 64 + lane) * 8) = hv;
}

// Main GEMM. grid = (MBLK, KSPLIT), block = 256 (4 waves).
// Wave w owns rows [w*64, w*64+64) of the block's 256-row tile (4 strips of
// 16) x all N=64 (4 ntiles) => 16 mfma_f32_16x16x32_f16 per K32 step,
// acc = 4x4 f32x4 = 64 regs. B staged via global_load_lds, double-buffered
// per K64 chunk. Results atomically added into pre-zeroed out (K-split).
__global__ __launch_bounds__(256, 2) void poly_gemm(const float* __restrict__ z,
                                                    const _Float16* __restrict__ Wt,
                                                    float* __restrict__ out) {
    __shared__ __align__(16) _Float16 zm[256][8];   // sample-major z (for half8 loads)
    __shared__ __align__(16) _Float16 zT[8][256];   // transposed (conflict-free u16 reads)
    __shared__ __align__(16) _Float16 bbuf[2][8][512]; // 2 bufs x 8 frags x 1KB

    int tid  = threadIdx.x;
    int lane = tid & 63;
    int w    = tid >> 6;
    int mb   = blockIdx.x;
    int ks   = blockIdx.y;

    // stage z (f32 -> f16) for this block's 256 samples
    {
        const float* zp = z + ((size_t)(mb * 256 + tid)) * 8;
        float4 a = *(const float4*)zp;
        float4 b = *(const float4*)(zp + 4);
        half8 h;
        h[0] = (_Float16)a.x; h[1] = (_Float16)a.y;
        h[2] = (_Float16)a.z; h[3] = (_Float16)a.w;
        h[4] = (_Float16)b.x; h[5] = (_Float16)b.y;
        h[6] = (_Float16)b.z; h[7] = (_Float16)b.w;
        *(half8*)&zm[tid][0] = h;
#pragma unroll
        for (int j = 0; j < 8; ++j) zT[j][tid] = h[j];
    }
    __syncthreads();

    int quad = lane >> 4;
    int l16  = lane & 15;
    int mrow[4];
    half8 zv[4];
#pragma unroll
    for (int t = 0; t < 4; ++t) {
        mrow[t] = w * 64 + t * 16 + l16;
        zv[t]   = *(const half8*)&zm[mrow[t]][0];
    }

    f32x4 acc[4][4];
#pragma unroll
    for (int t = 0; t < 4; ++t)
#pragma unroll
        for (int nt = 0; nt < 4; ++nt) acc[t][nt] = (f32x4){0.f, 0.f, 0.f, 0.f};

    int c0 = (ks * NCHUNK) / KSPLIT;
    int c1 = ((ks + 1) * NCHUNK) / KSPLIT;

    auto prefetch = [&](int c) {
        // 8 frags (2 steps x 4 ntiles) per chunk; wave w issues frags 2w, 2w+1
#pragma unroll
        for (int i = 0; i < 2; ++i) {
            int f = w * 2 + i;
            const _Float16* gp = Wt + (size_t)(c * 8 + f) * 512 + lane * 8;
            __builtin_amdgcn_global_load_lds(
                (const __attribute__((address_space(1))) void*)gp,
                (__attribute__((address_space(3))) void*)&bbuf[c & 1][f][0],
                16, 0, 0);
        }
    };

    prefetch(c0);
    __syncthreads();   // drains vmcnt -> buf[c0&1] ready

    for (int c = c0; c < c1; ++c) {
        if (c + 1 < c1) prefetch(c + 1);
#pragma unroll
        for (int sl = 0; sl < 2; ++sl) {
            int s = c * 2 + sl;
            half8 bf[4];
#pragma unroll
            for (int nt = 0; nt < 4; ++nt)
                bf[nt] = *(const half8*)&bbuf[c & 1][sl * 4 + nt][lane * 8];
#pragma unroll
            for (int t = 0; t < 4; ++t) {
                int m = mrow[t];
                half8 av;
                if (s >= 147) {              // deg5 (incl. s=1171 pad: W=0 there)
                    int u = s - 147;
                    _Float16 f = zT[(u >> 7) & 7][m] * zT[(u >> 4) & 7][m];
                    f = f * zT[(u >> 1) & 7][m];
                    f = f * zT[((u & 1) << 2) + quad][m];
                    av = zv[t] * f;
                } else if (s >= 19) {        // deg4
                    int u = s - 19;
                    _Float16 f = zT[(u >> 4) & 7][m] * zT[(u >> 1) & 7][m];
                    f = f * zT[((u & 1) << 2) + quad][m];
                    av = zv[t] * f;
                } else if (s >= 3) {         // deg3
                    int u = s - 3;
                    _Float16 f = zT[(u >> 1) & 7][m] * zT[((u & 1) << 2) + quad][m];
                    av = zv[t] * f;
                } else if (s >= 1) {         // deg2
                    _Float16 f = zT[(s - 1) * 4 + quad][m];
                    av = zv[t] * f;
                } else {                     // s == 0: [z(8) | 1 | zeros]
                    if (quad == 0)      av = zv[t];
                    else if (quad == 1) { av = (half8){}; av[0] = (_Float16)1.f; }
                    else                av = (half8){};
                }
#pragma unroll
                for (int nt = 0; nt < 4; ++nt)
                    acc[t][nt] = __builtin_amdgcn_mfma_f32_16x16x32_f16(
                        av, bf[nt], acc[t][nt], 0, 0, 0);
            }
        }
        __syncthreads();   // buf reuse fence + drains next-chunk prefetch
    }

    // epilogue: C/D layout col=lane&15, row=(lane>>4)*4+reg
#pragma unroll
    for (int t = 0; t < 4; ++t) {
        int mbase = mb * 256 + w * 64 + t * 16 + quad * 4;
#pragma unroll
        for (int nt = 0; nt < 4; ++nt) {
            int col = nt * 16 + l16;
#pragma unroll
            for (int r = 0; r < 4; ++r)
                unsafeAtomicAdd(out + (size_t)(mbase + r) * 64 + col, acc[t][nt][r]);
        }
    }
}

extern "C" void kernel_launch(void* const* d_in, const int* in_sizes, int n_in,
                              void* d_out, int out_size, void* d_ws, size_t ws_size,
                              hipStream_t stream) {
    (void)in_sizes; (void)n_in; (void)ws_size;
    const float* z = (const float*)d_in[0];
    const float* W = (const float*)d_in[1];
    const float* b = (const float*)d_in[2];
    float* out = (float*)d_out;
    _Float16* Wt = (_Float16*)d_ws;   // needs NSTEP*4*64*8*2 = 4,800,512 B

    hipMemsetAsync(d_out, 0, (size_t)out_size * sizeof(float), stream);
    hipLaunchKernelGGL(convert_w, dim3(NSTEP), dim3(256), 0, stream, W, b, Wt);
    hipLaunchKernelGGL(poly_gemm, dim3(MBLK, KSPLIT), dim3(256), 0, stream,
                       z, Wt, out);
}

// Round 2
// 118.003 us; speedup vs baseline: 1.0833x; 1.0833x over previous
//
#include <hip/hip_runtime.h>

// ---------------------------------------------------------------------------
// PolyDecoder: out[4096,64] = polyfeats(z)[4096,37449] @ W^T + b
// f16 MFMA GEMM, A generated on the fly, B pre-tiled in workspace as
// lane-major fragments so the main loop needs NO LDS staging and NO barriers.
//
// Padded K layout (32-granular; W padded with zeros):
//   kpad [0,8)=z | 8=const(bias folded) | [9,32)=0 | [32,96)=z^2 |
//   [96,608)=z^3 | [608,4704)=z^4 | [4704,37472)=z^5 | [37472,37504)=0
// step s = kpad/32: 0 deg<=1 | 1..2 deg2 | 3..18 deg3 | 19..146 deg4 |
//                   147..1170 deg5 | 1171 pad
// ---------------------------------------------------------------------------

#define TOTAL_TERMS 37449
#define NSTEP 1172
#define KSPLIT 32
#define MBLK 16

typedef _Float16 half8 __attribute__((ext_vector_type(8)));
typedef float f32x4 __attribute__((ext_vector_type(4)));

// Coalesced tiled transpose W (f32, n-major) -> Wt (f16 fragments).
// Block handles 64 padded k (2 steps) x all 64 n.
// Fragment element (s,nt,lane,j) = W[nt*16+(lane&15)][orig(s*32+(lane>>4)*8+j)]
__global__ __launch_bounds__(256) void convert_w(const float* __restrict__ W,
                                                 const float* __restrict__ bias,
                                                 _Float16* __restrict__ Wt) {
    __shared__ _Float16 lds[64][72];   // [n][kk], +8 pad breaks bank alignment
    int tid  = threadIdx.x;
    int lane = tid & 63;
    int nq   = tid >> 6;               // 0..3
    int kb   = blockIdx.x * 64;
    int kp   = kb + lane;

    // classify padded index once per lane (reused for all 16 rows)
    int o, mode;                       // mode: 0=load W, 1=zero, 2=const+bias
    if (kp < 8)           { o = 1 + kp;            mode = 0; }
    else if (kp == 8)     { o = 0;                 mode = 2; }
    else if (kp < 32)     { o = 0;                 mode = 1; }
    else if (kp < 96)     { o = 9    + (kp - 32);  mode = 0; }
    else if (kp < 608)    { o = 73   + (kp - 96);  mode = 0; }
    else if (kp < 4704)   { o = 585  + (kp - 608); mode = 0; }
    else if (kp < 37472)  { o = 4681 + (kp - 4704);mode = 0; }
    else                  { o = 0;                 mode = 1; }

#pragma unroll
    for (int r = 0; r < 16; ++r) {
        int n = r * 4 + nq;
        const float* wrow = W + (size_t)n * TOTAL_TERMS;
        float v;
        if (mode == 1)      v = 0.f;
        else if (mode == 2) v = wrow[0] + bias[n];
        else                v = wrow[o];             // coalesced along lane
        lds[n][lane] = (_Float16)v;
    }
    __syncthreads();

    int quad = lane >> 4, l16 = lane & 15;
    int n = nq * 16 + l16;
#pragma unroll
    for (int sl = 0; sl < 2; ++sl) {
        int kk = sl * 32 + quad * 8;
        half8 hv;
#pragma unroll
        for (int j = 0; j < 8; ++j) hv[j] = lds[n][kk + j];
        int s = (kb >> 5) + sl;
        *(half8*)(Wt + ((size_t)(s * 4 + nq) * 64 + lane) * 8) = hv;  // coalesced
    }
}

// Main GEMM. grid=(MBLK,KSPLIT), block=256 (4 waves). Wave w: rows
// [w*64,w*64+64) x N=64 -> 16 mfma_f32_16x16x32_f16 per step, acc 4x4xf32x4.
// B fragments loaded straight to VGPRs (register double-buffer, no barriers).
__global__ __launch_bounds__(256, 2) void poly_gemm(const float* __restrict__ z,
                                                    const _Float16* __restrict__ Wt,
                                                    float* __restrict__ out) {
    __shared__ __align__(16) _Float16 zm[256][8];   // sample-major (half8 loads)
    __shared__ _Float16 zT[8][272];                 // digit-major; 272 => rows 8 banks apart

    int tid  = threadIdx.x;
    int lane = tid & 63;
    int w    = tid >> 6;
    int mb   = blockIdx.x;
    int ks   = blockIdx.y;

    {
        const float* zp = z + ((size_t)(mb * 256 + tid)) * 8;
        float4 a = *(const float4*)zp;
        float4 b4 = *(const float4*)(zp + 4);
        half8 h;
        h[0] = (_Float16)a.x;  h[1] = (_Float16)a.y;
        h[2] = (_Float16)a.z;  h[3] = (_Float16)a.w;
        h[4] = (_Float16)b4.x; h[5] = (_Float16)b4.y;
        h[6] = (_Float16)b4.z; h[7] = (_Float16)b4.w;
        *(half8*)&zm[tid][0] = h;
#pragma unroll
        for (int j = 0; j < 8; ++j) zT[j][tid] = h[j];
    }
    __syncthreads();

    int quad = lane >> 4;
    int l16  = lane & 15;
    int mrow[4];
    half8 zv[4];
#pragma unroll
    for (int t = 0; t < 4; ++t) {
        mrow[t] = w * 64 + t * 16 + l16;
        zv[t]   = *(const half8*)&zm[mrow[t]][0];
    }

    f32x4 acc[4][4];
#pragma unroll
    for (int t = 0; t < 4; ++t)
#pragma unroll
        for (int nt = 0; nt < 4; ++nt) acc[t][nt] = (f32x4){0.f, 0.f, 0.f, 0.f};

    int s0 = (ks * NSTEP) / KSPLIT;
    int s1 = ((ks + 1) * NSTEP) / KSPLIT;

    const _Float16* bp = Wt + (size_t)s0 * 2048 + (size_t)lane * 8;
    half8 bcur[4];
#pragma unroll
    for (int nt = 0; nt < 4; ++nt)
        bcur[nt] = *(const half8*)(bp + nt * 512);

    for (int s = s0; s < s1; ++s) {
        // prefetch next step's B into registers (clamped at the very end)
        const _Float16* bpn = bp + ((s + 1 < NSTEP) ? 2048 : 0);
        half8 bnext[4];
#pragma unroll
        for (int nt = 0; nt < 4; ++nt)
            bnext[nt] = *(const half8*)(bpn + nt * 512);

        half8 av[4];
        if (s == 0) {
#pragma unroll
            for (int t = 0; t < 4; ++t) {
                if (quad == 0)      av[t] = zv[t];
                else if (quad == 1) { av[t] = (half8){}; av[t][0] = (_Float16)1.f; }
                else                av[t] = (half8){};
            }
        } else {
            _Float16 f[4];
            if (s >= 147) {              // deg5 (s=1171 pad hits W=0, harmless)
                int u = s - 147;
                int r1 = (u >> 7) & 7, r2 = (u >> 4) & 7, r3 = (u >> 1) & 7;
                int r4 = ((u & 1) << 2) + quad;
#pragma unroll
                for (int t = 0; t < 4; ++t) {
                    int m = mrow[t];
                    _Float16 g = zT[r1][m] * zT[r2][m];
                    g = g * zT[r3][m];
                    f[t] = g * zT[r4][m];
                }
            } else if (s >= 19) {        // deg4
                int u = s - 19;
                int r1 = (u >> 4) & 7, r2 = (u >> 1) & 7;
                int r3 = ((u & 1) << 2) + quad;
#pragma unroll
                for (int t = 0; t < 4; ++t) {
                    int m = mrow[t];
                    _Float16 g = zT[r1][m] * zT[r2][m];
                    f[t] = g * zT[r3][m];
                }
            } else if (s >= 3) {         // deg3
                int u = s - 3;
                int r1 = (u >> 1) & 7;
                int r2 = ((u & 1) << 2) + quad;
#pragma unroll
                for (int t = 0; t < 4; ++t)
                    f[t] = zT[r1][mrow[t]] * zT[r2][mrow[t]];
            } else {                     // deg2: s in {1,2}
                int r1 = (s - 1) * 4 + quad;
#pragma unroll
                for (int t = 0; t < 4; ++t)
                    f[t] = zT[r1][mrow[t]];
            }
#pragma unroll
            for (int t = 0; t < 4; ++t)
#pragma unroll
                for (int j = 0; j < 8; ++j) av[t][j] = zv[t][j] * f[t];
        }

#pragma unroll
        for (int t = 0; t < 4; ++t)
#pragma unroll
            for (int nt = 0; nt < 4; ++nt)
                acc[t][nt] = __builtin_amdgcn_mfma_f32_16x16x32_f16(
                    av[t], bcur[nt], acc[t][nt], 0, 0, 0);

        bp += 2048;
#pragma unroll
        for (int nt = 0; nt < 4; ++nt) bcur[nt] = bnext[nt];
    }

    // epilogue: C/D layout col=lane&15, row=(lane>>4)*4+reg
#pragma unroll
    for (int t = 0; t < 4; ++t) {
        int mbase = mb * 256 + w * 64 + t * 16 + quad * 4;
#pragma unroll
        for (int nt = 0; nt < 4; ++nt) {
            int col = nt * 16 + l16;
#pragma unroll
            for (int r = 0; r < 4; ++r)
                unsafeAtomicAdd(out + (size_t)(mbase + r) * 64 + col, acc[t][nt][r]);
        }
    }
}

extern "C" void kernel_launch(void* const* d_in, const int* in_sizes, int n_in,
                              void* d_out, int out_size, void* d_ws, size_t ws_size,
                              hipStream_t stream) {
    (void)in_sizes; (void)n_in; (void)ws_size;
    const float* z = (const float*)d_in[0];
    const float* W = (const float*)d_in[1];
    const float* b = (const float*)d_in[2];
    float* out = (float*)d_out;
    _Float16* Wt = (_Float16*)d_ws;   // NSTEP*2048*2 = 4,800,512 B

    hipMemsetAsync(d_out, 0, (size_t)out_size * sizeof(float), stream);
    hipLaunchKernelGGL(convert_w, dim3(NSTEP / 2), dim3(256), 0, stream, W, b, Wt);
    hipLaunchKernelGGL(poly_gemm, dim3(MBLK, KSPLIT), dim3(256), 0, stream,
                       z, Wt, out);
}

// Round 3
// 114.607 us; speedup vs baseline: 1.1154x; 1.0296x over previous
//
#include <hip/hip_runtime.h>

// ---------------------------------------------------------------------------
// PolyDecoder: out[4096,64] = polyfeats(z)[4096,37449] @ W^T + b
// f16 MFMA GEMM, A generated on the fly, B pre-tiled in workspace as
// lane-major fragments. Main loop: no LDS staging, no barriers, 2-deep
// register prefetch of B, 4 blocks/CU (16 waves/CU) for latency hiding.
//
// Padded K layout (32-granular; W padded with zeros):
//   kpad [0,8)=z | 8=const(bias folded) | [9,32)=0 | [32,96)=z^2 |
//   [96,608)=z^3 | [608,4704)=z^4 | [4704,37472)=z^5 | [37472,37504)=0
// step s = kpad/32: 0 deg<=1 | 1..2 deg2 | 3..18 deg3 | 19..146 deg4 |
//                   147..1170 deg5 | 1171 pad
// ---------------------------------------------------------------------------

#define TOTAL_TERMS 37449
#define NSTEP 1172
#define KSPLIT 32
#define MBLK 32              // 4096 / 128 rows per block

typedef _Float16 half8 __attribute__((ext_vector_type(8)));
typedef float f32x4 __attribute__((ext_vector_type(4)));

// Coalesced tiled transpose W (f32, n-major) -> Wt (f16 fragments).
// Block handles 64 padded k (2 steps) x all 64 n.
// Fragment element (s,nt,lane,j) = W[nt*16+(lane&15)][orig(s*32+(lane>>4)*8+j)]
__global__ __launch_bounds__(256) void convert_w(const float* __restrict__ W,
                                                 const float* __restrict__ bias,
                                                 _Float16* __restrict__ Wt) {
    __shared__ _Float16 lds[64][72];
    int tid  = threadIdx.x;
    int lane = tid & 63;
    int nq   = tid >> 6;               // 0..3
    int kb   = blockIdx.x * 64;
    int kp   = kb + lane;

    int o, mode;                       // mode: 0=load W, 1=zero, 2=const+bias
    if (kp < 8)           { o = 1 + kp;            mode = 0; }
    else if (kp == 8)     { o = 0;                 mode = 2; }
    else if (kp < 32)     { o = 0;                 mode = 1; }
    else if (kp < 96)     { o = 9    + (kp - 32);  mode = 0; }
    else if (kp < 608)    { o = 73   + (kp - 96);  mode = 0; }
    else if (kp < 4704)   { o = 585  + (kp - 608); mode = 0; }
    else if (kp < 37472)  { o = 4681 + (kp - 4704);mode = 0; }
    else                  { o = 0;                 mode = 1; }

#pragma unroll
    for (int r = 0; r < 16; ++r) {
        int n = r * 4 + nq;
        const float* wrow = W + (size_t)n * TOTAL_TERMS;
        float v;
        if (mode == 1)      v = 0.f;
        else if (mode == 2) v = wrow[0] + bias[n];
        else                v = wrow[o];             // coalesced along lane
        lds[n][lane] = (_Float16)v;
    }
    __syncthreads();

    int quad = lane >> 4, l16 = lane & 15;
    int n = nq * 16 + l16;
#pragma unroll
    for (int sl = 0; sl < 2; ++sl) {
        int kk = sl * 32 + quad * 8;
        half8 hv;
#pragma unroll
        for (int j = 0; j < 8; ++j) hv[j] = lds[n][kk + j];
        int s = (kb >> 5) + sl;
        *(half8*)(Wt + ((size_t)(s * 4 + nq) * 64 + lane) * 8) = hv;  // coalesced
    }
}

// Main GEMM. grid=(MBLK,KSPLIT)=1024 blocks, 4 waves each -> 16 waves/CU.
// Wave w: rows [w*32, w*32+32) of the block's 128-row tile x N=64
// -> 8 mfma_f32_16x16x32_f16 per K32 step, acc 2x4xf32x4 = 32 regs.
__global__ __launch_bounds__(256, 4) void poly_gemm(const float* __restrict__ z,
                                                    const _Float16* __restrict__ Wt,
                                                    float* __restrict__ out) {
    __shared__ __align__(16) _Float16 zm[128][8];   // sample-major (half8 loads)
    __shared__ _Float16 zT[8][144];   // digit-major; 288B row stride = 8 banks

    int tid  = threadIdx.x;
    int lane = tid & 63;
    int w    = tid >> 6;
    int mb   = blockIdx.x;
    int ks   = blockIdx.y;

    if (tid < 128) {
        const float* zp = z + ((size_t)(mb * 128 + tid)) * 8;
        float4 a = *(const float4*)zp;
        float4 b4 = *(const float4*)(zp + 4);
        half8 h;
        h[0] = (_Float16)a.x;  h[1] = (_Float16)a.y;
        h[2] = (_Float16)a.z;  h[3] = (_Float16)a.w;
        h[4] = (_Float16)b4.x; h[5] = (_Float16)b4.y;
        h[6] = (_Float16)b4.z; h[7] = (_Float16)b4.w;
        *(half8*)&zm[tid][0] = h;
#pragma unroll
        for (int j = 0; j < 8; ++j) zT[j][tid] = h[j];
    }
    __syncthreads();

    int quad = lane >> 4;
    int l16  = lane & 15;
    int mrow[2];
    half8 zv[2];
#pragma unroll
    for (int t = 0; t < 2; ++t) {
        mrow[t] = w * 32 + t * 16 + l16;
        zv[t]   = *(const half8*)&zm[mrow[t]][0];
    }

    f32x4 acc[2][4];
#pragma unroll
    for (int t = 0; t < 2; ++t)
#pragma unroll
        for (int nt = 0; nt < 4; ++nt) acc[t][nt] = (f32x4){0.f, 0.f, 0.f, 0.f};

    int s0 = (ks * NSTEP) / KSPLIT;
    int s1 = ((ks + 1) * NSTEP) / KSPLIT;

    const _Float16* base = Wt + (size_t)lane * 8;

    auto loadB = [&](int s, half8* dst) {
        const _Float16* p = base + (size_t)s * 2048;
#pragma unroll
        for (int nt = 0; nt < 4; ++nt)
            dst[nt] = *(const half8*)(p + nt * 512);
    };

    auto genA = [&](int s, half8* av) {
        if (s == 0) {
#pragma unroll
            for (int t = 0; t < 2; ++t) {
                if (quad == 0)      av[t] = zv[t];
                else if (quad == 1) { av[t] = (half8){}; av[t][0] = (_Float16)1.f; }
                else                av[t] = (half8){};
            }
            return;
        }
        _Float16 f[2];
        if (s >= 147) {              // deg5 (s=1171 pad hits W=0, harmless)
            int u = s - 147;
            int r1 = (u >> 7) & 7, r2 = (u >> 4) & 7, r3 = (u >> 1) & 7;
            int r4 = ((u & 1) << 2) + quad;
#pragma unroll
            for (int t = 0; t < 2; ++t) {
                int m = mrow[t];
                _Float16 g = zT[r1][m] * zT[r2][m];
                g = g * zT[r3][m];
                f[t] = g * zT[r4][m];
            }
        } else if (s >= 19) {        // deg4
            int u = s - 19;
            int r1 = (u >> 4) & 7, r2 = (u >> 1) & 7;
            int r3 = ((u & 1) << 2) + quad;
#pragma unroll
            for (int t = 0; t < 2; ++t) {
                int m = mrow[t];
                f[t] = (zT[r1][m] * zT[r2][m]) * zT[r3][m];
            }
        } else if (s >= 3) {         // deg3
            int u = s - 3;
            int r1 = (u >> 1) & 7;
            int r2 = ((u & 1) << 2) + quad;
#pragma unroll
            for (int t = 0; t < 2; ++t)
                f[t] = zT[r1][mrow[t]] * zT[r2][mrow[t]];
        } else {                     // deg2: s in {1,2}
            int r1 = (s - 1) * 4 + quad;
#pragma unroll
            for (int t = 0; t < 2; ++t)
                f[t] = zT[r1][mrow[t]];
        }
#pragma unroll
        for (int t = 0; t < 2; ++t)
#pragma unroll
            for (int j = 0; j < 8; ++j) av[t][j] = zv[t][j] * f[t];
    };

    auto mfma8 = [&](const half8* av, const half8* B) {
#pragma unroll
        for (int t = 0; t < 2; ++t)
#pragma unroll
            for (int nt = 0; nt < 4; ++nt)
                acc[t][nt] = __builtin_amdgcn_mfma_f32_16x16x32_f16(
                    av[t], B[nt], acc[t][nt], 0, 0, 0);
    };

    half8 B0[4], B1[4];
    loadB(s0, B0);
    loadB(s0 + 1, B1);               // s1-s0 >= 36, always valid

    int s = s0;
    for (; s + 1 < s1; s += 2) {
        half8 av[2];
        genA(s, av);
        mfma8(av, B0);
        if (s + 2 < s1) loadB(s + 2, B0);
        genA(s + 1, av);
        mfma8(av, B1);
        if (s + 3 < s1) loadB(s + 3, B1);
    }
    if (s < s1) {                    // odd remainder
        half8 av[2];
        genA(s, av);
        mfma8(av, B0);
    }

    // epilogue: C/D layout col=lane&15, row=(lane>>4)*4+reg
#pragma unroll
    for (int t = 0; t < 2; ++t) {
        int mbase = mb * 128 + w * 32 + t * 16 + quad * 4;
#pragma unroll
        for (int nt = 0; nt < 4; ++nt) {
            int col = nt * 16 + l16;
#pragma unroll
            for (int r = 0; r < 4; ++r)
                unsafeAtomicAdd(out + (size_t)(mbase + r) * 64 + col, acc[t][nt][r]);
        }
    }
}

extern "C" void kernel_launch(void* const* d_in, const int* in_sizes, int n_in,
                              void* d_out, int out_size, void* d_ws, size_t ws_size,
                              hipStream_t stream) {
    (void)in_sizes; (void)n_in; (void)ws_size;
    const float* z = (const float*)d_in[0];
    const float* W = (const float*)d_in[1];
    const float* b = (const float*)d_in[2];
    float* out = (float*)d_out;
    _Float16* Wt = (_Float16*)d_ws;   // NSTEP*2048*2 = 4,800,512 B

    hipMemsetAsync(d_out, 0, (size_t)out_size * sizeof(float), stream);
    hipLaunchKernelGGL(convert_w, dim3(NSTEP / 2), dim3(256), 0, stream, W, b, Wt);
    hipLaunchKernelGGL(poly_gemm, dim3(MBLK, KSPLIT), dim3(256), 0, stream,
                       z, Wt, out);
}